// Round 23
// baseline (95.751 us; speedup 1.0000x reference)
//
#include <hip/hip_runtime.h>

#define D_IN 256
#define D_OUT 128
#define NBINS 256
#define NB 256        // b3-role block count
#define BINCAP 5120   // per-bin capacity: mean 4096 + 16 sigma

typedef short bf16x8 __attribute__((ext_vector_type(8)));
typedef float f32x4 __attribute__((ext_vector_type(4)));

__device__ __forceinline__ unsigned short f2bf(float f) {
    unsigned int u = __float_as_uint(f);
    unsigned int r = (u + 0x7FFFu + ((u >> 16) & 1u)) >> 16;
    return (unsigned short)r;
}
__device__ __forceinline__ unsigned int pack2(float a, float b) {
    return (unsigned int)f2bf(a) | ((unsigned int)f2bf(b) << 16);
}
// async global->LDS, 16B per lane; LDS dest = wave-uniform base + lane*16
__device__ __forceinline__ void gload_lds16(const void* g, void* l) {
    __builtin_amdgcn_global_load_lds(
        (const __attribute__((address_space(1))) void*)g,
        (__attribute__((address_space(3))) void*)l, 16, 0, 0);
}

// ---- init: W^T bf16 convert (coalesced read) + zero bin cursors ----
__global__ __launch_bounds__(256) void k_init(const float* __restrict__ W,
                                              unsigned short* __restrict__ wt,
                                              int* __restrict__ bincursor) {
    int lin = blockIdx.x * 256 + threadIdx.x;   // 32768 total, 128 blocks
    int k  = lin >> 7;
    int nn = lin & 127;
    wt[nn * 256 + k] = f2bf(W[lin]);
    if (blockIdx.x == 0) bincursor[threadIdx.x] = 0;
}

// ===== fused, role-INTERLEAVED: bucket scatter (every 4th block) || 8-phase MFMA MLP =====
__global__ __launch_bounds__(256) void k_csrmlp(
    const int* __restrict__ src, const int* __restrict__ dst, int E, int epb,
    int* __restrict__ bincursor, int* __restrict__ ebuf,
    const float* __restrict__ x, const unsigned short* __restrict__ wt,
    const float* __restrict__ bias, float* __restrict__ h,
    unsigned char* __restrict__ hq, int n, int nmblk) {
    __shared__ char smem[32768];
    const int tid = threadIdx.x;
    const int bid = blockIdx.x;

    const bool is_b3 = ((bid & 3) == 3) && (bid < 1024);
    if (is_b3) {
        // ---- b3 role: LDS histogram -> one global atomic per bin -> LDS scatter ----
        const int b3id = bid >> 2;         // 0..255
        int* hist = (int*)smem;            // counts, then reused as cursor
        int* base = (int*)(smem + 1024);   // per-bin global base for this block
        hist[tid] = 0;
        __syncthreads();
        const int s = b3id * epb, e = min(s + epb, E);
        for (int i = s + tid; i < e; i += 256)
            atomicAdd(&hist[dst[i] >> 8], 1);
        __syncthreads();
        int hcnt = hist[tid];
        int p0 = (hcnt > 0) ? atomicAdd(&bincursor[tid], hcnt) : 0;
        base[tid] = tid * BINCAP + p0;
        __syncthreads();
        hist[tid] = 0;  // reuse as scatter cursor
        __syncthreads();
        for (int i = s + tid; i < e; i += 256) {
            int d = dst[i];
            int bin = d >> 8;
            int p = atomicAdd(&hist[bin], 1);
            ebuf[base[bin] + p] = (src[i] & 0xffff) | ((d & 255) << 16);
        }
        return;
    }

    // ---- MLP role: 8 phases of K=32, dbuf sx/swc, counted vmcnt + raw barriers ----
    const int tile = (bid < 1024) ? ((bid >> 2) * 3 + (bid & 3)) : (768 + (bid - 1024));
    if (tile >= nmblk) return;
    const int wid  = tid >> 6;
    const int lane = tid & 63;
    const int row0 = tile * 64;
    // LDS: sx[2][64][32]f32 @0,8K ; swc[2][128][32]bf16 @16K,24K

    f32x4 acc[8];
    #pragma unroll
    for (int fn = 0; fn < 8; ++fn) acc[fn] = (f32x4){0.f, 0.f, 0.f, 0.f};

    // STAGE(p): 2 x-chunks + 2 wt-chunks per thread (exactly 4 vmcnt events/wave)
    // swc swizzle key = (nr>>1)&3: same-parity rows get distinct slots -> 2-way max
    #define STAGE(p)                                                                   \
    {                                                                                  \
        const int k0s = (p) * 32;                                                      \
        char* sxb = smem + ((p) & 1) * 8192;                                           \
        char* swb = smem + 16384 + ((p) & 1) * 8192;                                   \
        _Pragma("unroll")                                                              \
        for (int i = 0; i < 2; ++i) {                                                  \
            int bi = i * 4 + wid;                                                      \
            int chunk = bi * 64 + lane;                                                \
            int r  = chunk >> 3;                                                       \
            int cs = chunk & 7;                                                        \
            int grow = min(row0 + r, n - 1);                                           \
            const float* g = x + (size_t)grow * D_IN + k0s + ((cs ^ (r & 7)) << 2);    \
            gload_lds16(g, sxb + bi * 1024);                                           \
        }                                                                              \
        _Pragma("unroll")                                                              \
        for (int i = 0; i < 2; ++i) {                                                  \
            int bi = i * 4 + wid;                                                      \
            int chunk = bi * 64 + lane;                                                \
            int nr = chunk >> 2;                                                       \
            int cs = chunk & 3;                                                        \
            const unsigned short* g =                                                  \
                wt + nr * D_IN + k0s + ((cs ^ ((nr >> 1) & 3)) << 3);                  \
            gload_lds16(g, swb + bi * 1024);                                           \
        }                                                                              \
    }

    STAGE(0);
    #pragma unroll
    for (int p = 0; p < 8; ++p) {
        if (p < 7) {
            STAGE(p + 1);
            asm volatile("s_waitcnt vmcnt(4)" ::: "memory");
        } else {
            asm volatile("s_waitcnt vmcnt(0)" ::: "memory");
        }
        __builtin_amdgcn_s_barrier();   // phase-p data visible to all waves

        const float* sxb = (const float*)(smem + (p & 1) * 8192);
        const unsigned short* swb =
            (const unsigned short*)(smem + 16384 + (p & 1) * 8192);
        int r  = wid * 16 + (lane & 15);
        int cs = (lane >> 4) * 2;
        float4 a0 = *reinterpret_cast<const float4*>(sxb + r * 32 + ((cs ^ (r & 7)) << 2));
        float4 a1 = *reinterpret_cast<const float4*>(sxb + r * 32 + (((cs + 1) ^ (r & 7)) << 2));
        union { unsigned int u[4]; bf16x8 v; } af;
        af.u[0] = pack2(a0.x, a0.y);
        af.u[1] = pack2(a0.z, a0.w);
        af.u[2] = pack2(a1.x, a1.y);
        af.u[3] = pack2(a1.z, a1.w);
        __builtin_amdgcn_s_setprio(1);
        #pragma unroll
        for (int fn = 0; fn < 8; ++fn) {
            int nr = fn * 16 + (lane & 15);
            int cb = lane >> 4;
            bf16x8 bfrag = *reinterpret_cast<const bf16x8*>(
                swb + nr * 32 + ((cb ^ ((nr >> 1) & 3)) << 3));
            acc[fn] = __builtin_amdgcn_mfma_f32_16x16x32_bf16(af.v, bfrag, acc[fn], 0, 0, 0);
        }
        __builtin_amdgcn_s_setprio(0);
        if (p < 7) __builtin_amdgcn_s_barrier();  // all waves done reading buf (p&1)
    }
    #undef STAGE

    // epilogue: bias + relu + L2 norm; f32 h + fixed-scale int8 (values in [0,1])
    float bias_r[8];
    #pragma unroll
    for (int fn = 0; fn < 8; ++fn) bias_r[fn] = bias[fn * 16 + (lane & 15)];
    const int colbase = lane & 15;
    const int rgrp = lane >> 4;
    #pragma unroll
    for (int reg = 0; reg < 4; ++reg) {
        int grow = row0 + wid * 16 + rgrp * 4 + reg;
        float v[8];
        float ss = 0.f;
        #pragma unroll
        for (int fn = 0; fn < 8; ++fn) {
            float t = fmaxf(acc[fn][reg] + bias_r[fn], 0.f);
            v[fn] = t;
            ss += t * t;
        }
        ss += __shfl_xor(ss, 1);
        ss += __shfl_xor(ss, 2);
        ss += __shfl_xor(ss, 4);
        ss += __shfl_xor(ss, 8);
        float sc = 1.f / fmaxf(sqrtf(ss), 1e-12f);
        if (grow < n) {
            #pragma unroll
            for (int fn = 0; fn < 8; ++fn) {
                float o = v[fn] * sc;
                h[(size_t)grow * D_OUT + fn * 16 + colbase] = o;
                hq[(size_t)grow * D_OUT + fn * 16 + colbase] =
                    (unsigned char)(int)rintf(o * 255.f);
            }
        }
    }
}

// ------ per-bucket fine sort -> csr, deg, offs (1024 threads; static bin bases) ------
__global__ __launch_bounds__(1024) void k_b4(const int* __restrict__ ebuf,
                                             const int* __restrict__ bincursor,
                                             int* __restrict__ deg, int* __restrict__ offs,
                                             int* __restrict__ csr, int n) {
    __shared__ int hist[NBINS];
    __shared__ int lo[NBINS];
    const int t = threadIdx.x;
    const int bin = blockIdx.x;
    const int base = bin * BINCAP;
    const int size = bincursor[bin];
    if (t < 256) hist[t] = 0;
    __syncthreads();
    for (int i = t; i < size; i += 1024)
        atomicAdd(&hist[(ebuf[base + i] >> 16) & 255], 1);
    __syncthreads();
    int hh = 0;
    if (t < 256) { hh = hist[t]; lo[t] = hh; }
    __syncthreads();
    for (int off = 1; off < 256; off <<= 1) {
        int v = (t >= off && t < 256) ? lo[t - off] : 0;
        __syncthreads();
        if (t < 256) lo[t] += v;
        __syncthreads();
    }
    if (t < 256) {
        int excl = lo[t] - hh;
        int gdst = bin * 256 + t;
        if (gdst < n) { deg[gdst] = hh; offs[gdst] = base + excl; }
        hist[t] = excl;  // reuse as cursor
    }
    __syncthreads();
    for (int i = t; i < size; i += 1024) {
        int pr = ebuf[base + i];
        int p = atomicAdd(&hist[(pr >> 16) & 255], 1);
        csr[base + p] = pr & 0xffff;
    }
}

// ---- agg pass 1: eighth-wave (8 lanes x 16B) per node; packed u16x2 byte sums ----
__global__ __launch_bounds__(256) void k_agg1(const unsigned char* __restrict__ hq,
                                              const int* __restrict__ offs,
                                              const int* __restrict__ deg,
                                              const int* __restrict__ csr,
                                              unsigned char* __restrict__ n1q, int n) {
    const int sub = threadIdx.x & 7;
    const int nper = blockDim.x >> 3;       // nodes per block (32)
    const int lid = threadIdx.x >> 3;
    for (int node = blockIdx.x * nper + lid; node < n; node += gridDim.x * nper) {
        int d = deg[node];
        int s = offs[node], e = s + d;
        unsigned int a0 = 0u, a1 = 0u, a2 = 0u, a3 = 0u;
        unsigned int a4 = 0u, a5 = 0u, a6 = 0u, a7 = 0u;
        int i = s;
        for (; i + 7 < e; i += 8) {
            #pragma unroll
            for (int j = 0; j < 8; ++j) {
                int u = csr[i + j];
                uint4 q = *reinterpret_cast<const uint4*>(hq + (size_t)u * D_OUT + sub * 16);
                a0 += q.x & 0x00FF00FFu; a1 += (q.x >> 8) & 0x00FF00FFu;
                a2 += q.y & 0x00FF00FFu; a3 += (q.y >> 8) & 0x00FF00FFu;
                a4 += q.z & 0x00FF00FFu; a5 += (q.z >> 8) & 0x00FF00FFu;
                a6 += q.w & 0x00FF00FFu; a7 += (q.w >> 8) & 0x00FF00FFu;
            }
        }
        for (; i < e; ++i) {
            int u = csr[i];
            uint4 q = *reinterpret_cast<const uint4*>(hq + (size_t)u * D_OUT + sub * 16);
            a0 += q.x & 0x00FF00FFu; a1 += (q.x >> 8) & 0x00FF00FFu;
            a2 += q.y & 0x00FF00FFu; a3 += (q.y >> 8) & 0x00FF00FFu;
            a4 += q.z & 0x00FF00FFu; a5 += (q.z >> 8) & 0x00FF00FFu;
            a6 += q.w & 0x00FF00FFu; a7 += (q.w >> 8) & 0x00FF00FFu;
        }
        float inv = 1.f / (float)max(d, 1);
        uint4 o;
        o.x = (unsigned int)(int)rintf((float)(a0 & 0xffffu) * inv)
            | ((unsigned int)(int)rintf((float)(a1 & 0xffffu) * inv) << 8)
            | ((unsigned int)(int)rintf((float)(a0 >> 16) * inv) << 16)
            | ((unsigned int)(int)rintf((float)(a1 >> 16) * inv) << 24);
        o.y = (unsigned int)(int)rintf((float)(a2 & 0xffffu) * inv)
            | ((unsigned int)(int)rintf((float)(a3 & 0xffffu) * inv) << 8)
            | ((unsigned int)(int)rintf((float)(a2 >> 16) * inv) << 16)
            | ((unsigned int)(int)rintf((float)(a3 >> 16) * inv) << 24);
        o.z = (unsigned int)(int)rintf((float)(a4 & 0xffffu) * inv)
            | ((unsigned int)(int)rintf((float)(a5 & 0xffffu) * inv) << 8)
            | ((unsigned int)(int)rintf((float)(a4 >> 16) * inv) << 16)
            | ((unsigned int)(int)rintf((float)(a5 >> 16) * inv) << 24);
        o.w = (unsigned int)(int)rintf((float)(a6 & 0xffffu) * inv)
            | ((unsigned int)(int)rintf((float)(a7 & 0xffffu) * inv) << 8)
            | ((unsigned int)(int)rintf((float)(a6 >> 16) * inv) << 16)
            | ((unsigned int)(int)rintf((float)(a7 >> 16) * inv) << 24);
        *reinterpret_cast<uint4*>(n1q + (size_t)node * D_OUT + sub * 16) = o;
    }
}

// ---- agg pass 2: out = (0.7*own + 0.3*mean)/255; eighth-wave per node ----
__global__ __launch_bounds__(256) void k_agg2(const unsigned char* __restrict__ n1q,
                                              const int* __restrict__ offs,
                                              const int* __restrict__ deg,
                                              const int* __restrict__ csr,
                                              float* __restrict__ out_m, int n) {
    const int sub = threadIdx.x & 7;
    const int nper = blockDim.x >> 3;
    const int lid = threadIdx.x >> 3;
    const float s255 = 1.f / 255.f;
    for (int node = blockIdx.x * nper + lid; node < n; node += gridDim.x * nper) {
        int d = deg[node];
        int s = offs[node], e = s + d;
        unsigned int a0 = 0u, a1 = 0u, a2 = 0u, a3 = 0u;
        unsigned int a4 = 0u, a5 = 0u, a6 = 0u, a7 = 0u;
        int i = s;
        for (; i + 7 < e; i += 8) {
            #pragma unroll
            for (int j = 0; j < 8; ++j) {
                int u = csr[i + j];
                uint4 q = *reinterpret_cast<const uint4*>(n1q + (size_t)u * D_OUT + sub * 16);
                a0 += q.x & 0x00FF00FFu; a1 += (q.x >> 8) & 0x00FF00FFu;
                a2 += q.y & 0x00FF00FFu; a3 += (q.y >> 8) & 0x00FF00FFu;
                a4 += q.z & 0x00FF00FFu; a5 += (q.z >> 8) & 0x00FF00FFu;
                a6 += q.w & 0x00FF00FFu; a7 += (q.w >> 8) & 0x00FF00FFu;
            }
        }
        for (; i < e; ++i) {
            int u = csr[i];
            uint4 q = *reinterpret_cast<const uint4*>(n1q + (size_t)u * D_OUT + sub * 16);
            a0 += q.x & 0x00FF00FFu; a1 += (q.x >> 8) & 0x00FF00FFu;
            a2 += q.y & 0x00FF00FFu; a3 += (q.y >> 8) & 0x00FF00FFu;
            a4 += q.z & 0x00FF00FFu; a5 += (q.z >> 8) & 0x00FF00FFu;
            a6 += q.w & 0x00FF00FFu; a7 += (q.w >> 8) & 0x00FF00FFu;
        }
        float inv = 1.f / (float)max(d, 1);
        uint4 own = *reinterpret_cast<const uint4*>(n1q + (size_t)node * D_OUT + sub * 16);
        float4 o0, o1, o2, o3;
        o0.x = (0.7f * (float)(own.x & 0xffu)         + 0.3f * (float)(a0 & 0xffffu) * inv) * s255;
        o0.y = (0.7f * (float)((own.x >> 8) & 0xffu)  + 0.3f * (float)(a1 & 0xffffu) * inv) * s255;
        o0.z = (0.7f * (float)((own.x >> 16) & 0xffu) + 0.3f * (float)(a0 >> 16) * inv) * s255;
        o0.w = (0.7f * (float)(own.x >> 24)           + 0.3f * (float)(a1 >> 16) * inv) * s255;
        o1.x = (0.7f * (float)(own.y & 0xffu)         + 0.3f * (float)(a2 & 0xffffu) * inv) * s255;
        o1.y = (0.7f * (float)((own.y >> 8) & 0xffu)  + 0.3f * (float)(a3 & 0xffffu) * inv) * s255;
        o1.z = (0.7f * (float)((own.y >> 16) & 0xffu) + 0.3f * (float)(a2 >> 16) * inv) * s255;
        o1.w = (0.7f * (float)(own.y >> 24)           + 0.3f * (float)(a3 >> 16) * inv) * s255;
        o2.x = (0.7f * (float)(own.z & 0xffu)         + 0.3f * (float)(a4 & 0xffffu) * inv) * s255;
        o2.y = (0.7f * (float)((own.z >> 8) & 0xffu)  + 0.3f * (float)(a5 & 0xffffu) * inv) * s255;
        o2.z = (0.7f * (float)((own.z >> 16) & 0xffu) + 0.3f * (float)(a4 >> 16) * inv) * s255;
        o2.w = (0.7f * (float)(own.z >> 24)           + 0.3f * (float)(a5 >> 16) * inv) * s255;
        o3.x = (0.7f * (float)(own.w & 0xffu)         + 0.3f * (float)(a6 & 0xffffu) * inv) * s255;
        o3.y = (0.7f * (float)((own.w >> 8) & 0xffu)  + 0.3f * (float)(a7 & 0xffffu) * inv) * s255;
        o3.z = (0.7f * (float)((own.w >> 16) & 0xffu) + 0.3f * (float)(a6 >> 16) * inv) * s255;
        o3.w = (0.7f * (float)(own.w >> 24)           + 0.3f * (float)(a7 >> 16) * inv) * s255;
        float* op = out_m + (size_t)node * D_OUT + sub * 16;
        *reinterpret_cast<float4*>(op)      = o0;
        *reinterpret_cast<float4*>(op + 4)  = o1;
        *reinterpret_cast<float4*>(op + 8)  = o2;
        *reinterpret_cast<float4*>(op + 12) = o3;
    }
}

static inline size_t align_up(size_t v, size_t a) { return (v + a - 1) & ~(a - 1); }

extern "C" void kernel_launch(void* const* d_in, const int* in_sizes, int n_in,
                              void* d_out, int out_size, void* d_ws, size_t ws_size,
                              hipStream_t stream) {
    const float* x  = (const float*)d_in[0];
    const float* W  = (const float*)d_in[1];
    const float* b  = (const float*)d_in[2];
    const int* src  = (const int*)d_in[3];
    const int* dst  = (const int*)d_in[4];

    const int n = in_sizes[0] / D_IN;   // 50000
    const int E = in_sizes[3];          // 800000

    float* out_h = (float*)d_out;                       // [n,128] f32
    float* out_m = out_h + (size_t)n * D_OUT;           // [n,128] f32

    // workspace carve-up
    char* ws = (char*)d_ws;
    size_t off = 0;
    int* bincursor = (int*)(ws + off); off = align_up(off + NBINS * 4, 256);
    int* ebuf      = (int*)(ws + off); off = align_up(off + (size_t)NBINS * BINCAP * 4, 256);
    int* csr       = (int*)(ws + off); off = align_up(off + (size_t)NBINS * BINCAP * 4, 256);
    int* deg       = (int*)(ws + off); off = align_up(off + (size_t)n * 4, 256);
    int* offs      = (int*)(ws + off); off = align_up(off + (size_t)n * 4, 256);
    unsigned short* wt = (unsigned short*)(ws + off); off = align_up(off + (size_t)D_OUT * D_IN * 2, 256);
    unsigned char* hq  = (unsigned char*)(ws + off); off = align_up(off + (size_t)n * D_OUT, 256);
    unsigned char* n1q = (unsigned char*)(ws + off); off = align_up(off + (size_t)n * D_OUT, 256);
    (void)ws_size;

    const int epb = (E + NB - 1) / NB;      // 3125
    const int nbuckets = (n + 255) / 256;   // 196
    const int nmblk = (n + 63) / 64;        // 782

    k_init<<<(D_OUT * D_IN) / 256, 256, 0, stream>>>(W, wt, bincursor);
    // grid: 1024 interleaved (3 MLP : 1 b3) + 14 extra MLP blocks = 1038
    k_csrmlp<<<1024 + (nmblk - 768), 256, 0, stream>>>(src, dst, E, epb, bincursor, ebuf,
                                                       x, wt, b, out_h, hq, n, nmblk);
    k_b4<<<nbuckets, 1024, 0, stream>>>(ebuf, bincursor, deg, offs, csr, n);

    // eighth-wave per node: 32 nodes per 256-thread block; grid-stride, capped
    const int agg_blocks_full = (n + 31) / 32;           // 1563
    const int agg_blocks = min(agg_blocks_full, 1568);
    k_agg1<<<agg_blocks, 256, 0, stream>>>(hq, offs, deg, csr, n1q, n);
    k_agg2<<<agg_blocks, 256, 0, stream>>>(n1q, offs, deg, csr, out_m, n);
}

// Round 24
// 89.737 us; speedup vs baseline: 1.0670x; 1.0670x over previous
//
#include <hip/hip_runtime.h>

#define D_IN 256
#define D_OUT 128
#define NBINS 256
#define NB 256        // b3-role block count
#define BINCAP 5120   // per-bin capacity: mean 4096 + 16 sigma

typedef short bf16x8 __attribute__((ext_vector_type(8)));
typedef float f32x4 __attribute__((ext_vector_type(4)));

__device__ __forceinline__ unsigned short f2bf(float f) {
    unsigned int u = __float_as_uint(f);
    unsigned int r = (u + 0x7FFFu + ((u >> 16) & 1u)) >> 16;
    return (unsigned short)r;
}
__device__ __forceinline__ unsigned int pack2(float a, float b) {
    return (unsigned int)f2bf(a) | ((unsigned int)f2bf(b) << 16);
}
// async global->LDS, 16B per lane; LDS dest = wave-uniform base + lane*16
__device__ __forceinline__ void gload_lds16(const void* g, void* l) {
    __builtin_amdgcn_global_load_lds(
        (const __attribute__((address_space(1))) void*)g,
        (__attribute__((address_space(3))) void*)l, 16, 0, 0);
}

// ---- init: W^T bf16 convert (coalesced read) + zero bin cursors ----
__global__ __launch_bounds__(256) void k_init(const float* __restrict__ W,
                                              unsigned short* __restrict__ wt,
                                              int* __restrict__ bincursor) {
    int lin = blockIdx.x * 256 + threadIdx.x;   // 32768 total, 128 blocks
    int k  = lin >> 7;
    int nn = lin & 127;
    wt[nn * 256 + k] = f2bf(W[lin]);
    if (blockIdx.x == 0) bincursor[threadIdx.x] = 0;
}

// ===== fused: bucket scatter w/ atomic reservation (0..NB-1) || 8-phase MFMA MLP =====
__global__ __launch_bounds__(256) void k_csrmlp(
    const int* __restrict__ src, const int* __restrict__ dst, int E, int epb,
    int* __restrict__ bincursor, int* __restrict__ ebuf,
    const float* __restrict__ x, const unsigned short* __restrict__ wt,
    const float* __restrict__ bias, float* __restrict__ h,
    unsigned char* __restrict__ hq, int n, int nmblk) {
    __shared__ char smem[32768];
    const int tid = threadIdx.x;
    const int bid = blockIdx.x;

    if (bid < NB) {
        // ---- b3 role: LDS histogram -> one global atomic per bin -> LDS scatter ----
        int* hist = (int*)smem;            // counts, then reused as cursor
        int* base = (int*)(smem + 1024);   // per-bin global base for this block
        hist[tid] = 0;
        __syncthreads();
        const int s = bid * epb, e = min(s + epb, E);
        for (int i = s + tid; i < e; i += 256)
            atomicAdd(&hist[dst[i] >> 8], 1);
        __syncthreads();
        int hcnt = hist[tid];
        int p0 = (hcnt > 0) ? atomicAdd(&bincursor[tid], hcnt) : 0;
        base[tid] = tid * BINCAP + p0;
        __syncthreads();
        hist[tid] = 0;  // reuse as scatter cursor
        __syncthreads();
        for (int i = s + tid; i < e; i += 256) {
            int d = dst[i];
            int bin = d >> 8;
            int p = atomicAdd(&hist[bin], 1);
            ebuf[base[bin] + p] = (src[i] & 0xffff) | ((d & 255) << 16);
        }
        return;
    }

    // ---- MLP role: 8 phases of K=32, dbuf sx/swc, counted vmcnt + raw barriers ----
    const int tile = bid - NB;
    if (tile >= nmblk) return;
    const int wid  = tid >> 6;
    const int lane = tid & 63;
    const int row0 = tile * 64;
    // LDS: sx[2][64][32]f32 @0,8K ; swc[2][128][32]bf16 @16K,24K

    f32x4 acc[8];
    #pragma unroll
    for (int fn = 0; fn < 8; ++fn) acc[fn] = (f32x4){0.f, 0.f, 0.f, 0.f};

    // STAGE(p): 2 x-chunks + 2 wt-chunks per thread (exactly 4 vmcnt events/wave)
    // swc swizzle key = (nr>>1)&3: same-parity rows get distinct slots -> 2-way max
    #define STAGE(p)                                                                   \
    {                                                                                  \
        const int k0s = (p) * 32;                                                      \
        char* sxb = smem + ((p) & 1) * 8192;                                           \
        char* swb = smem + 16384 + ((p) & 1) * 8192;                                   \
        _Pragma("unroll")                                                              \
        for (int i = 0; i < 2; ++i) {                                                  \
            int bi = i * 4 + wid;                                                      \
            int chunk = bi * 64 + lane;                                                \
            int r  = chunk >> 3;                                                       \
            int cs = chunk & 7;                                                        \
            int grow = min(row0 + r, n - 1);                                           \
            const float* g = x + (size_t)grow * D_IN + k0s + ((cs ^ (r & 7)) << 2);    \
            gload_lds16(g, sxb + bi * 1024);                                           \
        }                                                                              \
        _Pragma("unroll")                                                              \
        for (int i = 0; i < 2; ++i) {                                                  \
            int bi = i * 4 + wid;                                                      \
            int chunk = bi * 64 + lane;                                                \
            int nr = chunk >> 2;                                                       \
            int cs = chunk & 3;                                                        \
            const unsigned short* g =                                                  \
                wt + nr * D_IN + k0s + ((cs ^ ((nr >> 1) & 3)) << 3);                  \
            gload_lds16(g, swb + bi * 1024);                                           \
        }                                                                              \
    }

    STAGE(0);
    #pragma unroll
    for (int p = 0; p < 8; ++p) {
        if (p < 7) {
            STAGE(p + 1);
            asm volatile("s_waitcnt vmcnt(4)" ::: "memory");
        } else {
            asm volatile("s_waitcnt vmcnt(0)" ::: "memory");
        }
        __builtin_amdgcn_s_barrier();   // phase-p data visible to all waves

        const float* sxb = (const float*)(smem + (p & 1) * 8192);
        const unsigned short* swb =
            (const unsigned short*)(smem + 16384 + (p & 1) * 8192);
        int r  = wid * 16 + (lane & 15);
        int cs = (lane >> 4) * 2;
        float4 a0 = *reinterpret_cast<const float4*>(sxb + r * 32 + ((cs ^ (r & 7)) << 2));
        float4 a1 = *reinterpret_cast<const float4*>(sxb + r * 32 + (((cs + 1) ^ (r & 7)) << 2));
        union { unsigned int u[4]; bf16x8 v; } af;
        af.u[0] = pack2(a0.x, a0.y);
        af.u[1] = pack2(a0.z, a0.w);
        af.u[2] = pack2(a1.x, a1.y);
        af.u[3] = pack2(a1.z, a1.w);
        __builtin_amdgcn_s_setprio(1);
        #pragma unroll
        for (int fn = 0; fn < 8; ++fn) {
            int nr = fn * 16 + (lane & 15);
            int cb = lane >> 4;
            bf16x8 bfrag = *reinterpret_cast<const bf16x8*>(
                swb + nr * 32 + ((cb ^ ((nr >> 1) & 3)) << 3));
            acc[fn] = __builtin_amdgcn_mfma_f32_16x16x32_bf16(af.v, bfrag, acc[fn], 0, 0, 0);
        }
        __builtin_amdgcn_s_setprio(0);
        if (p < 7) __builtin_amdgcn_s_barrier();  // all waves done reading buf (p&1)
    }
    #undef STAGE

    // epilogue: bias + relu + L2 norm; f32 h + fixed-scale int8 (values in [0,1])
    float bias_r[8];
    #pragma unroll
    for (int fn = 0; fn < 8; ++fn) bias_r[fn] = bias[fn * 16 + (lane & 15)];
    const int colbase = lane & 15;
    const int rgrp = lane >> 4;
    #pragma unroll
    for (int reg = 0; reg < 4; ++reg) {
        int grow = row0 + wid * 16 + rgrp * 4 + reg;
        float v[8];
        float ss = 0.f;
        #pragma unroll
        for (int fn = 0; fn < 8; ++fn) {
            float t = fmaxf(acc[fn][reg] + bias_r[fn], 0.f);
            v[fn] = t;
            ss += t * t;
        }
        ss += __shfl_xor(ss, 1);
        ss += __shfl_xor(ss, 2);
        ss += __shfl_xor(ss, 4);
        ss += __shfl_xor(ss, 8);
        float sc = 1.f / fmaxf(sqrtf(ss), 1e-12f);
        if (grow < n) {
            #pragma unroll
            for (int fn = 0; fn < 8; ++fn) {
                float o = v[fn] * sc;
                h[(size_t)grow * D_OUT + fn * 16 + colbase] = o;
                hq[(size_t)grow * D_OUT + fn * 16 + colbase] =
                    (unsigned char)(int)rintf(o * 255.f);
            }
        }
    }
}

// ------ per-bucket fine sort -> csr, deg, offs (512 threads; static bin bases) ------
__global__ __launch_bounds__(512) void k_b4(const int* __restrict__ ebuf,
                                            const int* __restrict__ bincursor,
                                            int* __restrict__ deg, int* __restrict__ offs,
                                            int* __restrict__ csr, int n) {
    __shared__ int hist[NBINS];
    __shared__ int lo[NBINS];
    const int t = threadIdx.x;
    const int bin = blockIdx.x;
    const int base = bin * BINCAP;
    const int size = bincursor[bin];
    if (t < 256) hist[t] = 0;
    __syncthreads();
    for (int i = t; i < size; i += 512)
        atomicAdd(&hist[(ebuf[base + i] >> 16) & 255], 1);
    __syncthreads();
    int hh = 0;
    if (t < 256) { hh = hist[t]; lo[t] = hh; }
    __syncthreads();
    for (int off = 1; off < 256; off <<= 1) {
        int v = (t >= off && t < 256) ? lo[t - off] : 0;
        __syncthreads();
        if (t < 256) lo[t] += v;
        __syncthreads();
    }
    if (t < 256) {
        int excl = lo[t] - hh;
        int gdst = bin * 256 + t;
        if (gdst < n) { deg[gdst] = hh; offs[gdst] = base + excl; }
        hist[t] = excl;  // reuse as cursor
    }
    __syncthreads();
    for (int i = t; i < size; i += 512) {
        int pr = ebuf[base + i];
        int p = atomicAdd(&hist[(pr >> 16) & 255], 1);
        csr[base + p] = pr & 0xffff;
    }
}

// ---- agg pass 1: eighth-wave (8 lanes x 16B) per node; packed u16x2 byte sums ----
__global__ __launch_bounds__(256) void k_agg1(const unsigned char* __restrict__ hq,
                                              const int* __restrict__ offs,
                                              const int* __restrict__ deg,
                                              const int* __restrict__ csr,
                                              unsigned char* __restrict__ n1q, int n) {
    const int sub = threadIdx.x & 7;
    const int nper = blockDim.x >> 3;       // nodes per block (32)
    const int lid = threadIdx.x >> 3;
    for (int node = blockIdx.x * nper + lid; node < n; node += gridDim.x * nper) {
        int d = deg[node];
        int s = offs[node], e = s + d;
        unsigned int a0 = 0u, a1 = 0u, a2 = 0u, a3 = 0u;
        unsigned int a4 = 0u, a5 = 0u, a6 = 0u, a7 = 0u;
        int i = s;
        for (; i + 7 < e; i += 8) {
            #pragma unroll
            for (int j = 0; j < 8; ++j) {
                int u = csr[i + j];
                uint4 q = *reinterpret_cast<const uint4*>(hq + (size_t)u * D_OUT + sub * 16);
                a0 += q.x & 0x00FF00FFu; a1 += (q.x >> 8) & 0x00FF00FFu;
                a2 += q.y & 0x00FF00FFu; a3 += (q.y >> 8) & 0x00FF00FFu;
                a4 += q.z & 0x00FF00FFu; a5 += (q.z >> 8) & 0x00FF00FFu;
                a6 += q.w & 0x00FF00FFu; a7 += (q.w >> 8) & 0x00FF00FFu;
            }
        }
        for (; i < e; ++i) {
            int u = csr[i];
            uint4 q = *reinterpret_cast<const uint4*>(hq + (size_t)u * D_OUT + sub * 16);
            a0 += q.x & 0x00FF00FFu; a1 += (q.x >> 8) & 0x00FF00FFu;
            a2 += q.y & 0x00FF00FFu; a3 += (q.y >> 8) & 0x00FF00FFu;
            a4 += q.z & 0x00FF00FFu; a5 += (q.z >> 8) & 0x00FF00FFu;
            a6 += q.w & 0x00FF00FFu; a7 += (q.w >> 8) & 0x00FF00FFu;
        }
        float inv = 1.f / (float)max(d, 1);
        uint4 o;
        o.x = (unsigned int)(int)rintf((float)(a0 & 0xffffu) * inv)
            | ((unsigned int)(int)rintf((float)(a1 & 0xffffu) * inv) << 8)
            | ((unsigned int)(int)rintf((float)(a0 >> 16) * inv) << 16)
            | ((unsigned int)(int)rintf((float)(a1 >> 16) * inv) << 24);
        o.y = (unsigned int)(int)rintf((float)(a2 & 0xffffu) * inv)
            | ((unsigned int)(int)rintf((float)(a3 & 0xffffu) * inv) << 8)
            | ((unsigned int)(int)rintf((float)(a2 >> 16) * inv) << 16)
            | ((unsigned int)(int)rintf((float)(a3 >> 16) * inv) << 24);
        o.z = (unsigned int)(int)rintf((float)(a4 & 0xffffu) * inv)
            | ((unsigned int)(int)rintf((float)(a5 & 0xffffu) * inv) << 8)
            | ((unsigned int)(int)rintf((float)(a4 >> 16) * inv) << 16)
            | ((unsigned int)(int)rintf((float)(a5 >> 16) * inv) << 24);
        o.w = (unsigned int)(int)rintf((float)(a6 & 0xffffu) * inv)
            | ((unsigned int)(int)rintf((float)(a7 & 0xffffu) * inv) << 8)
            | ((unsigned int)(int)rintf((float)(a6 >> 16) * inv) << 16)
            | ((unsigned int)(int)rintf((float)(a7 >> 16) * inv) << 24);
        *reinterpret_cast<uint4*>(n1q + (size_t)node * D_OUT + sub * 16) = o;
    }
}

// ---- agg pass 2: out = (0.7*own + 0.3*mean)/255; eighth-wave per node ----
__global__ __launch_bounds__(256) void k_agg2(const unsigned char* __restrict__ n1q,
                                              const int* __restrict__ offs,
                                              const int* __restrict__ deg,
                                              const int* __restrict__ csr,
                                              float* __restrict__ out_m, int n) {
    const int sub = threadIdx.x & 7;
    const int nper = blockDim.x >> 3;
    const int lid = threadIdx.x >> 3;
    const float s255 = 1.f / 255.f;
    for (int node = blockIdx.x * nper + lid; node < n; node += gridDim.x * nper) {
        int d = deg[node];
        int s = offs[node], e = s + d;
        unsigned int a0 = 0u, a1 = 0u, a2 = 0u, a3 = 0u;
        unsigned int a4 = 0u, a5 = 0u, a6 = 0u, a7 = 0u;
        int i = s;
        for (; i + 7 < e; i += 8) {
            #pragma unroll
            for (int j = 0; j < 8; ++j) {
                int u = csr[i + j];
                uint4 q = *reinterpret_cast<const uint4*>(n1q + (size_t)u * D_OUT + sub * 16);
                a0 += q.x & 0x00FF00FFu; a1 += (q.x >> 8) & 0x00FF00FFu;
                a2 += q.y & 0x00FF00FFu; a3 += (q.y >> 8) & 0x00FF00FFu;
                a4 += q.z & 0x00FF00FFu; a5 += (q.z >> 8) & 0x00FF00FFu;
                a6 += q.w & 0x00FF00FFu; a7 += (q.w >> 8) & 0x00FF00FFu;
            }
        }
        for (; i < e; ++i) {
            int u = csr[i];
            uint4 q = *reinterpret_cast<const uint4*>(n1q + (size_t)u * D_OUT + sub * 16);
            a0 += q.x & 0x00FF00FFu; a1 += (q.x >> 8) & 0x00FF00FFu;
            a2 += q.y & 0x00FF00FFu; a3 += (q.y >> 8) & 0x00FF00FFu;
            a4 += q.z & 0x00FF00FFu; a5 += (q.z >> 8) & 0x00FF00FFu;
            a6 += q.w & 0x00FF00FFu; a7 += (q.w >> 8) & 0x00FF00FFu;
        }
        float inv = 1.f / (float)max(d, 1);
        uint4 own = *reinterpret_cast<const uint4*>(n1q + (size_t)node * D_OUT + sub * 16);
        float4 o0, o1, o2, o3;
        o0.x = (0.7f * (float)(own.x & 0xffu)         + 0.3f * (float)(a0 & 0xffffu) * inv) * s255;
        o0.y = (0.7f * (float)((own.x >> 8) & 0xffu)  + 0.3f * (float)(a1 & 0xffffu) * inv) * s255;
        o0.z = (0.7f * (float)((own.x >> 16) & 0xffu) + 0.3f * (float)(a0 >> 16) * inv) * s255;
        o0.w = (0.7f * (float)(own.x >> 24)           + 0.3f * (float)(a1 >> 16) * inv) * s255;
        o1.x = (0.7f * (float)(own.y & 0xffu)         + 0.3f * (float)(a2 & 0xffffu) * inv) * s255;
        o1.y = (0.7f * (float)((own.y >> 8) & 0xffu)  + 0.3f * (float)(a3 & 0xffffu) * inv) * s255;
        o1.z = (0.7f * (float)((own.y >> 16) & 0xffu) + 0.3f * (float)(a2 >> 16) * inv) * s255;
        o1.w = (0.7f * (float)(own.y >> 24)           + 0.3f * (float)(a3 >> 16) * inv) * s255;
        o2.x = (0.7f * (float)(own.z & 0xffu)         + 0.3f * (float)(a4 & 0xffffu) * inv) * s255;
        o2.y = (0.7f * (float)((own.z >> 8) & 0xffu)  + 0.3f * (float)(a5 & 0xffffu) * inv) * s255;
        o2.z = (0.7f * (float)((own.z >> 16) & 0xffu) + 0.3f * (float)(a4 >> 16) * inv) * s255;
        o2.w = (0.7f * (float)(own.z >> 24)           + 0.3f * (float)(a5 >> 16) * inv) * s255;
        o3.x = (0.7f * (float)(own.w & 0xffu)         + 0.3f * (float)(a6 & 0xffffu) * inv) * s255;
        o3.y = (0.7f * (float)((own.w >> 8) & 0xffu)  + 0.3f * (float)(a7 & 0xffffu) * inv) * s255;
        o3.z = (0.7f * (float)((own.w >> 16) & 0xffu) + 0.3f * (float)(a6 >> 16) * inv) * s255;
        o3.w = (0.7f * (float)(own.w >> 24)           + 0.3f * (float)(a7 >> 16) * inv) * s255;
        float* op = out_m + (size_t)node * D_OUT + sub * 16;
        *reinterpret_cast<float4*>(op)      = o0;
        *reinterpret_cast<float4*>(op + 4)  = o1;
        *reinterpret_cast<float4*>(op + 8)  = o2;
        *reinterpret_cast<float4*>(op + 12) = o3;
    }
}

static inline size_t align_up(size_t v, size_t a) { return (v + a - 1) & ~(a - 1); }

extern "C" void kernel_launch(void* const* d_in, const int* in_sizes, int n_in,
                              void* d_out, int out_size, void* d_ws, size_t ws_size,
                              hipStream_t stream) {
    const float* x  = (const float*)d_in[0];
    const float* W  = (const float*)d_in[1];
    const float* b  = (const float*)d_in[2];
    const int* src  = (const int*)d_in[3];
    const int* dst  = (const int*)d_in[4];

    const int n = in_sizes[0] / D_IN;   // 50000
    const int E = in_sizes[3];          // 800000

    float* out_h = (float*)d_out;                       // [n,128] f32
    float* out_m = out_h + (size_t)n * D_OUT;           // [n,128] f32

    // workspace carve-up
    char* ws = (char*)d_ws;
    size_t off = 0;
    int* bincursor = (int*)(ws + off); off = align_up(off + NBINS * 4, 256);
    int* ebuf      = (int*)(ws + off); off = align_up(off + (size_t)NBINS * BINCAP * 4, 256);
    int* csr       = (int*)(ws + off); off = align_up(off + (size_t)NBINS * BINCAP * 4, 256);
    int* deg       = (int*)(ws + off); off = align_up(off + (size_t)n * 4, 256);
    int* offs      = (int*)(ws + off); off = align_up(off + (size_t)n * 4, 256);
    unsigned short* wt = (unsigned short*)(ws + off); off = align_up(off + (size_t)D_OUT * D_IN * 2, 256);
    unsigned char* hq  = (unsigned char*)(ws + off); off = align_up(off + (size_t)n * D_OUT, 256);
    unsigned char* n1q = (unsigned char*)(ws + off); off = align_up(off + (size_t)n * D_OUT, 256);
    (void)ws_size;

    const int epb = (E + NB - 1) / NB;      // 3125
    const int nbuckets = (n + 255) / 256;   // 196
    const int nmblk = (n + 63) / 64;        // 782

    k_init<<<(D_OUT * D_IN) / 256, 256, 0, stream>>>(W, wt, bincursor);
    k_csrmlp<<<NB + nmblk, 256, 0, stream>>>(src, dst, E, epb, bincursor, ebuf,
                                             x, wt, b, out_h, hq, n, nmblk);
    k_b4<<<nbuckets, 512, 0, stream>>>(ebuf, bincursor, deg, offs, csr, n);

    // eighth-wave per node: 32 nodes per 256-thread block; grid-stride, capped
    const int agg_blocks_full = (n + 31) / 32;           // 1563
    const int agg_blocks = min(agg_blocks_full, 1568);
    k_agg1<<<agg_blocks, 256, 0, stream>>>(hq, offs, deg, csr, n1q, n);
    k_agg2<<<agg_blocks, 256, 0, stream>>>(n1q, offs, deg, csr, out_m, n);
}